// Round 8
// baseline (498.448 us; speedup 1.0000x reference)
//
#include <hip/hip_runtime.h>

// BiGRU, B=512, T=512, D=16, H=64 — MFMA-batched recurrence.
// Backward direction needs only ONE cell step (ys_b[0] = GRUCell(x[:,T-1,:], 0)).
//
// R4/R7 plateau at 379us (~1780 cyc/step) with fp32 VALU matvec regardless of
// organization -> move the matvec to the matrix pipe. 16 batches/block:
// per step  [256 x 96] x [96 x 16]  via mfma_f32_16x16x32_bf16.
//  - precision: hi/lo bf16 split of W and state s; D += Whi*shi + Whi*slo +
//    Wlo*shi  (error ~2^-16 rel, fp32-equivalent; lo*lo dropped).
//  - s = [h(64); x_t(16); zero-pad(16..)] -> input projection folded into the
//    same MFMAs. n-gate keeps x-part (nx tile) and h-part (nh tile) separate
//    because r multiplies only the h-part.
//  - wave w owns j in [16w,16w+16): its C tiles give r,z,nh,nx for the SAME
//    (j,b) on the SAME lane -> gates fully in registers, no preact LDS trip.
//  - one barrier/step (parity-dbuf s); h fp32 in regs; x_{t+1} global prefetch.

typedef unsigned int uint32;
typedef unsigned short ushort16;
typedef __attribute__((ext_vector_type(8))) short bf16x8;
typedef __attribute__((ext_vector_type(4))) float f32x4;

#define Hh 64
#define Dd 16
#define Tt 512
#define Bb 512
#define NBat 16          // batches per block
#define SK 104           // padded row stride of s (ushorts): 208B, 16B-aligned

__device__ __forceinline__ ushort16 f2bf(float f) {
    uint32 u = __float_as_uint(f);
    return (ushort16)((u + 0x7FFFu + ((u >> 16) & 1u)) >> 16);
}
__device__ __forceinline__ float bf2f(ushort16 h) {
    return __uint_as_float(((uint32)h) << 16);
}
__device__ __forceinline__ float sigmoid_fast(float v) {
    return 1.0f / (1.0f + __expf(-v));
}
__device__ __forceinline__ float tanh_fast(float v) {
    float e = __expf(2.0f * v);
    return 1.0f - 2.0f / (e + 1.0f);
}
__device__ __forceinline__ f32x4 mfma16(bf16x8 a, bf16x8 b, f32x4 c) {
    return __builtin_amdgcn_mfma_f32_16x16x32_bf16(a, b, c, 0, 0, 0);
}
__device__ __forceinline__ float dot4(float4 a, float4 b) {
    return a.x * b.x + a.y * b.y + a.z * b.z + a.w * b.w;
}

// Build one A-fragment (hi+lo) for augmented weight row `row` (0..191 index into
// the 192-row W_hh/W_ih matrices), K-tile kt. mode: 0=r/z (W_hh k<64, W_ih 64..80),
// 1=nh (W_hh only), 2=nx (W_ih only).
__device__ __forceinline__ void build_frag(const float* __restrict__ w_hh,
                                           const float* __restrict__ w_ih,
                                           int row, int kt, int lane, int mode,
                                           bf16x8* fhi, bf16x8* flo) {
    const int kbase = kt * 32 + (lane >> 4) * 8;
    bf16x8 hi, lo;
#pragma unroll
    for (int i = 0; i < 8; ++i) {
        int k = kbase + i;
        float f = 0.0f;
        if (mode == 0) {
            if (k < 64)      f = w_hh[row * 64 + k];
            else if (k < 80) f = w_ih[row * 16 + (k - 64)];
        } else if (mode == 1) {
            if (k < 64)      f = w_hh[row * 64 + k];
        } else {
            if (k >= 64 && k < 80) f = w_ih[row * 16 + (k - 64)];
        }
        ushort16 h = f2bf(f);
        ushort16 l2 = f2bf(f - bf2f(h));
        hi[i] = (short)h;
        lo[i] = (short)l2;
    }
    *fhi = hi; *flo = lo;
}

__global__ __launch_bounds__(256, 1)
void bigru_mfma_kernel(const float* __restrict__ x,
                       const float* __restrict__ w_ih_f, const float* __restrict__ w_hh_f,
                       const float* __restrict__ b_ih_f, const float* __restrict__ b_hh_f,
                       const float* __restrict__ w_ih_b, const float* __restrict__ w_hh_b,
                       const float* __restrict__ b_ih_b, const float* __restrict__ b_hh_b,
                       const float* __restrict__ fc_w,  const float* __restrict__ fc_b,
                       float* __restrict__ out)
{
    const int tid  = threadIdx.x;
    const int l    = tid & 63;       // lane in wave
    const int w    = tid >> 6;       // wave 0..3
    const int q    = l >> 4;         // quad
    const int bc   = l & 15;         // batch column (B-frag n == C col)
    const int bbase = blockIdx.x * NBat;

    __shared__ __align__(16) ushort16 s_hi[2][NBat][SK];
    __shared__ __align__(16) ushort16 s_lo[2][NBat][SK];
    __shared__ __align__(16) float hfin[NBat][68];

    // ---- zero s (h region + zero-pad region; x region overwritten each step) ----
    {
        uint32* p1 = (uint32*)s_hi;
        uint32* p2 = (uint32*)s_lo;
        const int n32 = 2 * NBat * SK / 2;   // 1664 dwords per array
        for (int i = tid; i < n32; i += 256) { p1[i] = 0u; p2[i] = 0u; }
    }

    // ---- A-fragments (hi/lo) for this wave's j-slice, built once ----
    const int jb   = 16 * w;
    const int mrow = jb + (l & 15);  // A-side row within each gate block
    bf16x8 Ar_h[3], Ar_l[3], Az_h[3], Az_l[3], Anh_h[2], Anh_l[2], Anx_h, Anx_l;
#pragma unroll
    for (int kt = 0; kt < 3; ++kt) {
        build_frag(w_hh_f, w_ih_f, mrow,      kt, l, 0, &Ar_h[kt], &Ar_l[kt]);
        build_frag(w_hh_f, w_ih_f, 64 + mrow, kt, l, 0, &Az_h[kt], &Az_l[kt]);
    }
#pragma unroll
    for (int kt = 0; kt < 2; ++kt)
        build_frag(w_hh_f, w_ih_f, 128 + mrow, kt, l, 1, &Anh_h[kt], &Anh_l[kt]);
    build_frag(w_hh_f, w_ih_f, 128 + mrow, 2, l, 2, &Anx_h, &Anx_l);

    // ---- per-lane gate biases for the 4 C rows (j = jc..jc+3), h state ----
    const int jc = jb + q * 4;
    float br[4], bz[4], bxn[4], bhn[4], h[4];
#pragma unroll
    for (int r2 = 0; r2 < 4; ++r2) {
        int j = jc + r2;
        br[r2]  = b_ih_f[j]        + b_hh_f[j];
        bz[r2]  = b_ih_f[64 + j]   + b_hh_f[64 + j];
        bxn[r2] = b_ih_f[128 + j];
        bhn[r2] = b_hh_f[128 + j];
        h[r2]   = 0.0f;
    }

    // ---- x_0 into s[0] (h region stays zero) ----
    const int xb = tid & 15, xd = tid >> 4;
    const size_t xbase = ((size_t)(bbase + xb) * Tt) * Dd + xd;
    {
        float xv = x[xbase];           // t = 0
        ushort16 hx = f2bf(xv);
        s_hi[0][xb][64 + xd] = hx;
        s_lo[0][xb][64 + xd] = f2bf(xv - bf2f(hx));
    }
    __syncthreads();

    for (int t = 0; t < Tt; ++t) {
        const int par = t & 1, parn = par ^ 1;

        // prefetch x_{t+1} (clamped; value at t=511 is written but never read)
        const int tn = (t + 1 < Tt) ? (t + 1) : (Tt - 1);
        float xnf = x[xbase + (size_t)tn * Dd];

        // B-fragments: lane reads batch bc, 8 consecutive k at kt*32 + q*8
        bf16x8 Bh[3], Bl[3];
#pragma unroll
        for (int kt = 0; kt < 3; ++kt) {
            Bh[kt] = *(const bf16x8*)&s_hi[par][bc][kt * 32 + q * 8];
            Bl[kt] = *(const bf16x8*)&s_lo[par][bc][kt * 32 + q * 8];
        }

        f32x4 ar = {0,0,0,0}, az = {0,0,0,0}, anh = {0,0,0,0}, anx = {0,0,0,0};
#pragma unroll
        for (int kt = 0; kt < 3; ++kt) {
            ar = mfma16(Ar_h[kt], Bh[kt], ar);
            ar = mfma16(Ar_h[kt], Bl[kt], ar);
            ar = mfma16(Ar_l[kt], Bh[kt], ar);
            az = mfma16(Az_h[kt], Bh[kt], az);
            az = mfma16(Az_h[kt], Bl[kt], az);
            az = mfma16(Az_l[kt], Bh[kt], az);
        }
#pragma unroll
        for (int kt = 0; kt < 2; ++kt) {
            anh = mfma16(Anh_h[kt], Bh[kt], anh);
            anh = mfma16(Anh_h[kt], Bl[kt], anh);
            anh = mfma16(Anh_l[kt], Bh[kt], anh);
        }
        anx = mfma16(Anx_h, Bh[2], anx);
        anx = mfma16(Anx_h, Bl[2], anx);
        anx = mfma16(Anx_l, Bh[2], anx);

        // ---- gates entirely in registers (C rows = this lane's 4 j's) ----
        ushort16 hh[4], hl[4];
#pragma unroll
        for (int r2 = 0; r2 < 4; ++r2) {
            float rg = sigmoid_fast(ar[r2] + br[r2]);
            float zg = sigmoid_fast(az[r2] + bz[r2]);
            float ng = tanh_fast(anx[r2] + bxn[r2] + rg * (anh[r2] + bhn[r2]));
            h[r2] = ng + zg * (h[r2] - ng);
            ushort16 hb16 = f2bf(h[r2]);
            hh[r2] = hb16;
            hl[r2] = f2bf(h[r2] - bf2f(hb16));
        }
        // write h (4 consecutive j at jc, batch bc) packed as b64
        {
            uint2 ph, pl;
            ph.x = (uint32)hh[0] | ((uint32)hh[1] << 16);
            ph.y = (uint32)hh[2] | ((uint32)hh[3] << 16);
            pl.x = (uint32)hl[0] | ((uint32)hl[1] << 16);
            pl.y = (uint32)hl[2] | ((uint32)hl[3] << 16);
            *(uint2*)&s_hi[parn][bc][jc] = ph;
            *(uint2*)&s_lo[parn][bc][jc] = pl;
        }
        // write x_{t+1}
        {
            ushort16 hx = f2bf(xnf);
            s_hi[parn][xb][64 + xd] = hx;
            s_lo[parn][xb][64 + xd] = f2bf(xnf - bf2f(hx));
        }
        __syncthreads();
    }

    // ---- publish final forward h to LDS ----
    {
        float4 hv = make_float4(h[0], h[1], h[2], h[3]);
        *(float4*)&hfin[bc][jc] = hv;
    }
    __syncthreads();

    // ---- backward single cell step + fused FC: wave w handles batches 4w..4w+3 ----
    {
        const int j = l;
        float4 wq0[4], wq1[4], wq2[4];
        {
            const float4* p0 = (const float4*)(w_ih_b + (size_t)j         * Dd);
            const float4* p1 = (const float4*)(w_ih_b + (size_t)(64 + j)  * Dd);
            const float4* p2 = (const float4*)(w_ih_b + (size_t)(128 + j) * Dd);
#pragma unroll
            for (int qq = 0; qq < 4; ++qq) { wq0[qq] = p0[qq]; wq1[qq] = p1[qq]; wq2[qq] = p2[qq]; }
        }
        const float brb  = b_ih_b[j]        + b_hh_b[j];
        const float bzb  = b_ih_b[64 + j]   + b_hh_b[64 + j];
        const float bxnb = b_ih_b[128 + j];
        const float bhnb = b_hh_b[128 + j];
        const float fw1 = fc_w[j], fw2 = fc_w[64 + j];

#pragma unroll
        for (int p = 0; p < 4; ++p) {
            const int bl = 4 * w + p;
            const float4* xl = (const float4*)(x + ((size_t)(bbase + bl) * Tt + (Tt - 1)) * Dd);
            float ar2 = brb, az2 = bzb, axn2 = bxnb;
#pragma unroll
            for (int qq = 0; qq < 4; ++qq) {
                float4 xv = xl[qq];
                ar2  += dot4(wq0[qq], xv);
                az2  += dot4(wq1[qq], xv);
                axn2 += dot4(wq2[qq], xv);
            }
            float rb = sigmoid_fast(ar2);
            float zb = sigmoid_fast(az2);
            float nb = tanh_fast(axn2 + rb * bhnb);
            float hb = (1.0f - zb) * nb;     // h0 = 0

            float v = fw1 * hfin[bl][j] + fw2 * hb;
#pragma unroll
            for (int off = 32; off > 0; off >>= 1)
                v += __shfl_xor(v, off, 64);
            if (j == 0) out[bbase + bl] = v + fc_b[0];
        }
    }
}

extern "C" void kernel_launch(void* const* d_in, const int* in_sizes, int n_in,
                              void* d_out, int out_size, void* d_ws, size_t ws_size,
                              hipStream_t stream) {
    const float* x      = (const float*)d_in[0];
    const float* w_ih_f = (const float*)d_in[1];
    const float* w_hh_f = (const float*)d_in[2];
    const float* b_ih_f = (const float*)d_in[3];
    const float* b_hh_f = (const float*)d_in[4];
    const float* w_ih_b = (const float*)d_in[5];
    const float* w_hh_b = (const float*)d_in[6];
    const float* b_ih_b = (const float*)d_in[7];
    const float* b_hh_b = (const float*)d_in[8];
    const float* fc_w   = (const float*)d_in[9];
    const float* fc_b   = (const float*)d_in[10];

    bigru_mfma_kernel<<<dim3(Bb / NBat), dim3(256), 0, stream>>>(
        x, w_ih_f, w_hh_f, b_ih_f, b_hh_f,
        w_ih_b, w_hh_b, b_ih_b, b_hh_b, fc_w, fc_b,
        (float*)d_out);
}